// Round 1
// baseline (200.811 us; speedup 1.0000x reference)
//
#include <hip/hip_runtime.h>
#include <cstdint>
#include <cstddef>

#define BATCH 4
#define SEQ 2048
#define DIM 512

using floatx4 = __attribute__((ext_vector_type(4))) float;
using shortx8 = __attribute__((ext_vector_type(8))) short;

__device__ __forceinline__ ushort f2bf(float f) {
    union { float f; uint32_t u; } v; v.f = f;
    uint32_t r = v.u + 0x7FFFu + ((v.u >> 16) & 1u);
    return (ushort)(r >> 16);
}

// ---------------- conversion kernels ----------------

__global__ void cvt_f32_bf16_k(const float* __restrict__ in, ushort* __restrict__ out, int n4) {
    int i = blockIdx.x * blockDim.x + threadIdx.x;
    if (i < n4) {
        float4 v = ((const float4*)in)[i];
        ((ushort4*)out)[i] = make_ushort4(f2bf(v.x), f2bf(v.y), f2bf(v.z), f2bf(v.w));
    }
}

__global__ void prep_w_k(const float* __restrict__ Wq, const float* __restrict__ Wk,
                         const float* __restrict__ Wv, ushort* __restrict__ wcat) {
    int i = blockIdx.x * blockDim.x + threadIdx.x;   // < 3*512*512 = 786432
    int which = i >> 18;                              // 512*512 = 2^18
    int inner = i & 0x3FFFF;
    const float* w = (which == 0) ? Wq : (which == 1) ? Wk : Wv;
    wcat[i] = f2bf(w[inner]);
}

__global__ void prep_bias_k(const float* __restrict__ bq, const float* __restrict__ bk,
                            const float* __restrict__ bv, float* __restrict__ bcat) {
    int i = blockIdx.x * blockDim.x + threadIdx.x;
    if (i < 512)       bcat[i] = bq[i];
    else if (i < 1024) bcat[i] = bk[i - 512];
    else if (i < 1536) bcat[i] = bv[i - 1024];
}

// v stored as qkv[(b*SEQ+j)*1536 + 1024 + e]  ->  vt[b][e][j]  (ld SEQ)
__global__ void transpose_v_k(const ushort* __restrict__ qkv, ushort* __restrict__ vt) {
    __shared__ ushort t[32][33];
    int b  = blockIdx.z;
    int j0 = blockIdx.x * 32;
    int e0 = blockIdx.y * 32;
    for (int r = threadIdx.y; r < 32; r += 8)
        t[r][threadIdx.x] = qkv[(size_t)(b * SEQ + j0 + r) * 1536 + 1024 + e0 + threadIdx.x];
    __syncthreads();
    for (int r = threadIdx.y; r < 32; r += 8)
        vt[((size_t)b * DIM + e0 + r) * SEQ + j0 + threadIdx.x] = t[threadIdx.x][r];
}

// ---------------- GEMM: C[m,n] = alpha * sum_k A[m,k]*B[n,k] (+bias[n]) ----------------
// NT layout: both A and B contiguous along k. 128x128 tile, BK=32, 256 thr = 4 waves 2x2,
// each wave 64x64 as 4x4 of 16x16x32 bf16 MFMA.

template<bool BF16_OUT, bool BIAS>
__global__ __launch_bounds__(256, 2)
void gemm_nt_k(const ushort* __restrict__ A, const ushort* __restrict__ B,
               void* __restrict__ Cout, const float* __restrict__ bias,
               int lda, int ldb, int ldc, int K, float alpha,
               long sA, long sB, long sC)
{
    __shared__ __align__(16) ushort As[128 * 32];
    __shared__ __align__(16) ushort Bs[128 * 32];
    const int bz = blockIdx.z;
    const ushort* Ab = A + (size_t)bz * sA;
    const ushort* Bb = B + (size_t)bz * sB;
    const int m0 = blockIdx.y * 128;
    const int n0 = blockIdx.x * 128;
    const int tid  = threadIdx.x;
    const int lane = tid & 63;
    const int wave = tid >> 6;
    const int wm = (wave >> 1) * 64;
    const int wn = (wave & 1) * 64;
    const int quad = lane >> 4;
    const int l16  = lane & 15;

    floatx4 acc[4][4];
#pragma unroll
    for (int i = 0; i < 4; i++)
#pragma unroll
        for (int j = 0; j < 4; j++)
            acc[i][j] = (floatx4){0.f, 0.f, 0.f, 0.f};

    for (int k0 = 0; k0 < K; k0 += 32) {
        // stage 128x32 bf16 tiles of A and B: 2 x 256 threads x 16B each
#pragma unroll
        for (int r = 0; r < 2; ++r) {
            int idx = r * 256 + tid;                   // 0..511
            const ushort* ga = Ab + (size_t)(m0 + (idx >> 2)) * lda + k0 + (idx & 3) * 8;
            const ushort* gb = Bb + (size_t)(n0 + (idx >> 2)) * ldb + k0 + (idx & 3) * 8;
            __builtin_amdgcn_global_load_lds(
                (const __attribute__((address_space(1))) uint32_t*)ga,
                (__attribute__((address_space(3))) uint32_t*)(As + idx * 8), 16, 0, 0);
            __builtin_amdgcn_global_load_lds(
                (const __attribute__((address_space(1))) uint32_t*)gb,
                (__attribute__((address_space(3))) uint32_t*)(Bs + idx * 8), 16, 0, 0);
        }
        __syncthreads();

        shortx8 af[4], bf[4];
#pragma unroll
        for (int mi = 0; mi < 4; mi++)
            af[mi] = *(const shortx8*)&As[(wm + mi * 16 + l16) * 32 + quad * 8];
#pragma unroll
        for (int ni = 0; ni < 4; ni++)
            bf[ni] = *(const shortx8*)&Bs[(wn + ni * 16 + l16) * 32 + quad * 8];
#pragma unroll
        for (int mi = 0; mi < 4; mi++)
#pragma unroll
            for (int ni = 0; ni < 4; ni++)
                acc[mi][ni] = __builtin_amdgcn_mfma_f32_16x16x32_bf16(af[mi], bf[ni], acc[mi][ni], 0, 0, 0);
        __syncthreads();
    }

    float bvv[4];
    if (BIAS) {
#pragma unroll
        for (int ni = 0; ni < 4; ni++) bvv[ni] = bias[n0 + wn + ni * 16 + l16];
    }
#pragma unroll
    for (int mi = 0; mi < 4; mi++) {
#pragma unroll
        for (int ni = 0; ni < 4; ni++) {
#pragma unroll
            for (int r = 0; r < 4; r++) {
                int row = m0 + wm + mi * 16 + quad * 4 + r;   // C/D: row = quad*4+reg
                int col = n0 + wn + ni * 16 + l16;            //      col = lane&15
                float v = acc[mi][ni][r] * alpha;
                if (BIAS) v += bvv[ni];
                if (BF16_OUT)
                    ((ushort*)Cout)[(size_t)bz * sC + (size_t)row * ldc + col] = f2bf(v);
                else
                    ((float*)Cout)[(size_t)bz * sC + (size_t)row * ldc + col] = v;
            }
        }
    }
}

// ---------------- softmax: one wave per row of 2048, fp32 in, bf16 out ----------------

__global__ void softmax_rows_k(const float* __restrict__ S, ushort* __restrict__ P) {
    int row  = blockIdx.x * 4 + (threadIdx.x >> 6);
    int lane = threadIdx.x & 63;
    const float* src = S + (size_t)row * SEQ;
    float4 v[8];
    float mx = -1e30f;
#pragma unroll
    for (int j = 0; j < 8; j++) {
        v[j] = *(const float4*)(src + lane * 4 + j * 256);
        mx = fmaxf(mx, fmaxf(fmaxf(v[j].x, v[j].y), fmaxf(v[j].z, v[j].w)));
    }
#pragma unroll
    for (int off = 32; off; off >>= 1) mx = fmaxf(mx, __shfl_xor(mx, off));
    float sum = 0.f;
#pragma unroll
    for (int j = 0; j < 8; j++) {
        v[j].x = __expf(v[j].x - mx);
        v[j].y = __expf(v[j].y - mx);
        v[j].z = __expf(v[j].z - mx);
        v[j].w = __expf(v[j].w - mx);
        sum += v[j].x + v[j].y + v[j].z + v[j].w;
    }
#pragma unroll
    for (int off = 32; off; off >>= 1) sum += __shfl_xor(sum, off);
    float inv = 1.0f / sum;
    ushort* dst = P + (size_t)row * SEQ;
#pragma unroll
    for (int j = 0; j < 8; j++) {
        ((ushort4*)(dst + lane * 4 + j * 256))[0] =
            make_ushort4(f2bf(v[j].x * inv), f2bf(v[j].y * inv), f2bf(v[j].z * inv), f2bf(v[j].w * inv));
    }
}

// ---------------- launch ----------------

extern "C" void kernel_launch(void* const* d_in, const int* in_sizes, int n_in,
                              void* d_out, int out_size, void* d_ws, size_t ws_size,
                              hipStream_t stream) {
    const float* x  = (const float*)d_in[0];
    const float* Wq = (const float*)d_in[1];
    const float* bq = (const float*)d_in[2];
    const float* Wk = (const float*)d_in[3];
    const float* bk = (const float*)d_in[4];
    const float* Wv = (const float*)d_in[5];
    const float* bv = (const float*)d_in[6];
    float* out = (float*)d_out;
    char* ws = (char*)d_ws;

    // workspace layout (256B aligned offsets)
    ushort* xb   = (ushort*)(ws);                 //  8192*512   bf16 =  8,388,608 B
    ushort* wcat = (ushort*)(ws + 8388608);       //  1536*512   bf16 =  1,572,864 B
    float*  bcat = (float* )(ws + 9961472);       //  1536       f32  =      6,144 B
    ushort* qkvb = (ushort*)(ws + 9967616);       //  8192*1536  bf16 = 25,165,824 B
    ushort* vt   = (ushort*)(ws + 35133440);      //  4*512*2048 bf16 =  8,388,608 B
    float*  Sb   = (float* )(ws + 43522048);      //  4*2048*2048 f32 = 67,108,864 B
    ushort* Pb   = (ushort*)(ws + 110630912);     //  4*2048*2048 bf16= 33,554,432 B
    // total = 144,185,344 B

    cvt_f32_bf16_k<<<4096, 256, 0, stream>>>(x, xb, 1048576);
    prep_w_k<<<3072, 256, 0, stream>>>(Wq, Wk, Wv, wcat);
    prep_bias_k<<<6, 256, 0, stream>>>(bq, bk, bv, bcat);

    // QKV projection: [8192,1536] = x[8192,512] @ wcat[1536,512]^T + bcat, bf16 out
    gemm_nt_k<true, true><<<dim3(12, 64, 1), 256, 0, stream>>>(
        xb, wcat, qkvb, bcat, 512, 512, 1536, 512, 1.0f, 0, 0, 0);

    transpose_v_k<<<dim3(64, 16, 4), dim3(32, 8), 0, stream>>>(qkvb, vt);

    // scores: per batch S[2048,2048] = scale * q @ k^T, fp32 out
    const float scale = 0.04419417382415922f;  // 1/sqrt(512)
    gemm_nt_k<false, false><<<dim3(16, 16, 4), 256, 0, stream>>>(
        qkvb, qkvb + 512, Sb, nullptr, 1536, 1536, 2048, 512, scale,
        (long)SEQ * 1536, (long)SEQ * 1536, (long)SEQ * SEQ);

    softmax_rows_k<<<2048, 256, 0, stream>>>(Sb, Pb);

    // out: per batch O[2048,512] = P[2048,2048] @ vt[512,2048]^T, fp32 out
    gemm_nt_k<false, false><<<dim3(4, 16, 4), 256, 0, stream>>>(
        Pb, vt, out, nullptr, 2048, 2048, 512, 2048, 1.0f,
        (long)SEQ * SEQ, (long)DIM * SEQ, (long)SEQ * DIM);
}

// Round 3
// 199.013 us; speedup vs baseline: 1.0090x; 1.0090x over previous
//
#include <hip/hip_runtime.h>
#include <cstdint>
#include <cstddef>

#define BATCH 4
#define SEQ 2048
#define DIM 512

using floatx4 = __attribute__((ext_vector_type(4))) float;
using shortx8 = __attribute__((ext_vector_type(8))) short;
using halfx8  = __attribute__((ext_vector_type(8))) _Float16;

__device__ __forceinline__ ushort f2bf(float f) {
    union { float f; uint32_t u; } v; v.f = f;
    uint32_t r = v.u + 0x7FFFu + ((v.u >> 16) & 1u);
    return (ushort)(r >> 16);
}
__device__ __forceinline__ ushort f2h(float f) {
    _Float16 h = (_Float16)f;
    return __builtin_bit_cast(unsigned short, h);
}

// ---------------- prep: x->bf16, W->bf16 cat, bias cat (one kernel) ----------------
// x: 4*2048*512 = 4,194,304 floats = 1,048,576 float4
// W: 3*512*512  =   786,432 floats =   196,608 float4
// b: 3*512      =     1,536 floats =       384 float4
__global__ void prep_k(const float* __restrict__ x,
                       const float* __restrict__ Wq, const float* __restrict__ Wk,
                       const float* __restrict__ Wv,
                       const float* __restrict__ bq, const float* __restrict__ bk,
                       const float* __restrict__ bv,
                       ushort* __restrict__ xb, ushort* __restrict__ wcat,
                       float* __restrict__ bcat) {
    int i = blockIdx.x * 256 + threadIdx.x;
    if (i < 1048576) {                        // x float4
        float4 v = ((const float4*)x)[i];
        ((ushort4*)xb)[i] = make_ushort4(f2bf(v.x), f2bf(v.y), f2bf(v.z), f2bf(v.w));
    } else if (i < 1048576 + 196608) {        // W: 3 * 65536 float4
        int j = i - 1048576;
        int which = j >> 16;
        const float* w = (which == 0) ? Wq : (which == 1) ? Wk : Wv;
        float4 v = ((const float4*)w)[j & 0xFFFF];
        ((ushort4*)wcat)[j] = make_ushort4(f2bf(v.x), f2bf(v.y), f2bf(v.z), f2bf(v.w));
    } else if (i < 1048576 + 196608 + 384) {  // bias: 3 * 128 float4
        int j = i - 1245184;
        const float* bsrc = (j < 128) ? bq : (j < 256) ? bk : bv;
        ((float4*)bcat)[j] = ((const float4*)bsrc)[j & 127];
    }
}

// v stored as qkv[(b*SEQ+j)*1536 + 1024 + e] (fp16) -> vt[b][e][j]  (ld SEQ)
__global__ void transpose_v_k(const ushort* __restrict__ qkv, ushort* __restrict__ vt) {
    __shared__ ushort t[32][33];
    int b  = blockIdx.z;
    int j0 = blockIdx.x * 32;
    int e0 = blockIdx.y * 32;
    for (int r = threadIdx.y; r < 32; r += 8)
        t[r][threadIdx.x] = qkv[(size_t)(b * SEQ + j0 + r) * 1536 + 1024 + e0 + threadIdx.x];
    __syncthreads();
    for (int r = threadIdx.y; r < 32; r += 8)
        vt[((size_t)b * DIM + e0 + r) * SEQ + j0 + threadIdx.x] = t[threadIdx.x][r];
}

// ---------------- pipelined NT GEMM, 128x128xBK32, swizzled LDS ----------------
// EPI: 0 = QKV (+bias, bf16 q/k cols<1024, fp16 v cols>=1024)
//      1 = SCORES (store fp16 exp(acc*alpha), accumulate fp32 row sums)
//      2 = PV split-K partial (fp32 partial store; bz = b*2 + kchunk)

template<int EPI, bool F16>
__global__ __launch_bounds__(256, 2)
void gemm_k(const ushort* __restrict__ A, const ushort* __restrict__ B,
            void* __restrict__ Cout, const float* __restrict__ bias,
            float* __restrict__ rowsum,
            int lda, int ldb, int ldc, int kIters, float alpha,
            long sA, long sB, long sC)
{
    __shared__ __align__(16) ushort As[2][128 * 32];
    __shared__ __align__(16) ushort Bs[2][128 * 32];
    __shared__ float rsum[128];

    const int tid = threadIdx.x;
    const int bz = blockIdx.z;
    int b, kofs, slab;
    if (EPI == 2) { b = bz >> 1; kofs = (bz & 1) << 10; slab = ((bz & 1) << 2) + b; }
    else          { b = bz; kofs = 0; slab = bz; }
    const ushort* Ab = A + (size_t)b * sA + kofs;
    const ushort* Bb = B + (size_t)b * sB + kofs;

    const int m0 = blockIdx.y * 128;
    const int n0 = blockIdx.x * 128;
    const int lane = tid & 63, wave = tid >> 6;
    const int wm = (wave >> 1) * 64, wn = (wave & 1) * 64;
    const int quad = lane >> 4, l16 = lane & 15;
    const int swz = (l16 >> 1) & 3;

    // staging: slot s holds global chunk (s&3) ^ ((row>>1)&3) of row s>>2
    const int s0 = tid, s1 = tid + 256;
    const int r0 = s0 >> 2, r1 = s1 >> 2;
    const int kc0 = (s0 & 3) ^ ((r0 >> 1) & 3);
    const int kc1 = (s1 & 3) ^ ((r1 >> 1) & 3);
    const ushort* gA0 = Ab + (size_t)(m0 + r0) * lda + kc0 * 8;
    const ushort* gA1 = Ab + (size_t)(m0 + r1) * lda + kc1 * 8;
    const ushort* gB0 = Bb + (size_t)(n0 + r0) * ldb + kc0 * 8;
    const ushort* gB1 = Bb + (size_t)(n0 + r1) * ldb + kc1 * 8;

#define STAGE(kk, bufi) do {                                                              \
    int ko = (kk) * 32;                                                                   \
    __builtin_amdgcn_global_load_lds((const __attribute__((address_space(1))) uint32_t*)(gA0 + ko), \
        (__attribute__((address_space(3))) uint32_t*)(&As[bufi][s0 * 8]), 16, 0, 0);      \
    __builtin_amdgcn_global_load_lds((const __attribute__((address_space(1))) uint32_t*)(gA1 + ko), \
        (__attribute__((address_space(3))) uint32_t*)(&As[bufi][s1 * 8]), 16, 0, 0);      \
    __builtin_amdgcn_global_load_lds((const __attribute__((address_space(1))) uint32_t*)(gB0 + ko), \
        (__attribute__((address_space(3))) uint32_t*)(&Bs[bufi][s0 * 8]), 16, 0, 0);      \
    __builtin_amdgcn_global_load_lds((const __attribute__((address_space(1))) uint32_t*)(gB1 + ko), \
        (__attribute__((address_space(3))) uint32_t*)(&Bs[bufi][s1 * 8]), 16, 0, 0);      \
} while (0)

    int ofsA[4], ofsB[4];
#pragma unroll
    for (int mi = 0; mi < 4; mi++)
        ofsA[mi] = ((wm + mi * 16 + l16) * 4 + (quad ^ swz)) * 8;
#pragma unroll
    for (int ni = 0; ni < 4; ni++)
        ofsB[ni] = ((wn + ni * 16 + l16) * 4 + (quad ^ swz)) * 8;

    floatx4 acc[4][4];
#pragma unroll
    for (int i = 0; i < 4; i++)
#pragma unroll
        for (int j = 0; j < 4; j++)
            acc[i][j] = (floatx4){0.f, 0.f, 0.f, 0.f};

    if (EPI == 1 && tid < 128) rsum[tid] = 0.f;

    STAGE(0, 0);
    for (int it = 0; it < kIters; ++it) {
        __syncthreads();                       // loads into buf are done; prev reads retired
        const int buf = it & 1;
        if (it + 1 < kIters) STAGE(it + 1, buf ^ 1);   // in flight during MFMA burst
        if constexpr (F16) {
            halfx8 af[4], bfr[4];
#pragma unroll
            for (int mi = 0; mi < 4; mi++) af[mi] = *(const halfx8*)&As[buf][ofsA[mi]];
#pragma unroll
            for (int ni = 0; ni < 4; ni++) bfr[ni] = *(const halfx8*)&Bs[buf][ofsB[ni]];
#pragma unroll
            for (int mi = 0; mi < 4; mi++)
#pragma unroll
                for (int ni = 0; ni < 4; ni++)
                    acc[mi][ni] = __builtin_amdgcn_mfma_f32_16x16x32_f16(af[mi], bfr[ni], acc[mi][ni], 0, 0, 0);
        } else {
            shortx8 af[4], bfr[4];
#pragma unroll
            for (int mi = 0; mi < 4; mi++) af[mi] = *(const shortx8*)&As[buf][ofsA[mi]];
#pragma unroll
            for (int ni = 0; ni < 4; ni++) bfr[ni] = *(const shortx8*)&Bs[buf][ofsB[ni]];
#pragma unroll
            for (int mi = 0; mi < 4; mi++)
#pragma unroll
                for (int ni = 0; ni < 4; ni++)
                    acc[mi][ni] = __builtin_amdgcn_mfma_f32_16x16x32_bf16(af[mi], bfr[ni], acc[mi][ni], 0, 0, 0);
        }
    }
#undef STAGE

    if constexpr (EPI == 0) {
        float bvv[4];
#pragma unroll
        for (int ni = 0; ni < 4; ni++) bvv[ni] = bias[n0 + wn + ni * 16 + l16];
#pragma unroll
        for (int mi = 0; mi < 4; mi++) {
#pragma unroll
            for (int ni = 0; ni < 4; ni++) {
                int col = n0 + wn + ni * 16 + l16;
#pragma unroll
                for (int r = 0; r < 4; r++) {
                    int row = m0 + wm + mi * 16 + quad * 4 + r;
                    float v = acc[mi][ni][r] + bvv[ni];
                    ((ushort*)Cout)[(size_t)row * ldc + col] = (col < 1024) ? f2bf(v) : f2h(v);
                }
            }
        }
    } else if constexpr (EPI == 1) {
#pragma unroll
        for (int mi = 0; mi < 4; mi++) {
#pragma unroll
            for (int r = 0; r < 4; r++) {
                int rl = wm + mi * 16 + quad * 4 + r;
                float ps = 0.f;
#pragma unroll
                for (int ni = 0; ni < 4; ni++) {
                    int col = n0 + wn + ni * 16 + l16;
                    float e = __expf(acc[mi][ni][r] * alpha);
                    ((ushort*)Cout)[(size_t)slab * sC + (size_t)(m0 + rl) * ldc + col] = f2h(e);
                    ps += e;
                }
                atomicAdd(&rsum[rl], ps);
            }
        }
        __syncthreads();
        if (tid < 128) atomicAdd(&rowsum[b * SEQ + m0 + tid], rsum[tid]);
    } else {
#pragma unroll
        for (int mi = 0; mi < 4; mi++) {
#pragma unroll
            for (int ni = 0; ni < 4; ni++) {
                int col = n0 + wn + ni * 16 + l16;
#pragma unroll
                for (int r = 0; r < 4; r++) {
                    int row = m0 + wm + mi * 16 + quad * 4 + r;
                    ((float*)Cout)[(size_t)slab * sC + (size_t)row * ldc + col] = acc[mi][ni][r];
                }
            }
        }
    }
}

// ---------------- reduce split-K partials + softmax normalization ----------------
__global__ void reduce_scale_k(const float* __restrict__ part, const float* __restrict__ rowsum,
                               float* __restrict__ out) {
    int i = blockIdx.x * 256 + threadIdx.x;      // float4 index, 1,048,576 total
    float4 a = ((const float4*)part)[i];
    float4 c = ((const float4*)(part + 4LL * SEQ * DIM))[i];
    float inv = 1.0f / rowsum[i >> 7];           // 128 float4 per row
    float4 o;
    o.x = (a.x + c.x) * inv;
    o.y = (a.y + c.y) * inv;
    o.z = (a.z + c.z) * inv;
    o.w = (a.w + c.w) * inv;
    ((float4*)out)[i] = o;
}

// ---------------- launch ----------------
extern "C" void kernel_launch(void* const* d_in, const int* in_sizes, int n_in,
                              void* d_out, int out_size, void* d_ws, size_t ws_size,
                              hipStream_t stream) {
    const float* x  = (const float*)d_in[0];
    const float* Wq = (const float*)d_in[1];
    const float* bq = (const float*)d_in[2];
    const float* Wk = (const float*)d_in[3];
    const float* bk = (const float*)d_in[4];
    const float* Wv = (const float*)d_in[5];
    const float* bv = (const float*)d_in[6];
    float* out = (float*)d_out;
    char* ws = (char*)d_ws;

    // workspace layout
    ushort* xb      = (ushort*)(ws);               //  8,388,608
    ushort* wcat    = (ushort*)(ws + 8388608);     //  1,572,864
    float*  bcat    = (float* )(ws + 9961472);     //      6,144
    ushort* qkvb    = (ushort*)(ws + 9967616);     // 25,165,824  (q,k bf16 | v fp16)
    ushort* vt      = (ushort*)(ws + 35133440);    //  8,388,608  fp16
    ushort* Pb      = (ushort*)(ws + 43522048);    // 33,554,432  fp16 exp(s)
    float*  rowsum  = (float* )(ws + 77076480);    //     32,768
    float*  partial = (float* )(ws + 77109248);    // 33,554,432
    // total 110,663,680

    hipMemsetAsync(rowsum, 0, 8192 * 4, stream);

    prep_k<<<4866, 256, 0, stream>>>(x, Wq, Wk, Wv, bq, bk, bv, xb, wcat, bcat);

    // QKV: [8192,1536] = xb @ wcat^T + bcat
    gemm_k<0, false><<<dim3(12, 64, 1), 256, 0, stream>>>(
        xb, wcat, qkvb, bcat, nullptr, 512, 512, 1536, 16, 1.0f, 0, 0, 0);

    transpose_v_k<<<dim3(64, 16, 4), dim3(32, 8), 0, stream>>>(qkvb, vt);

    // scores -> P' = exp(q@k^T * scale) fp16, rowsum fp32
    const float scale = 0.04419417382415922f;  // 1/sqrt(512)
    gemm_k<1, false><<<dim3(16, 16, 4), 256, 0, stream>>>(
        qkvb, qkvb + 512, Pb, nullptr, rowsum, 1536, 1536, 2048, 16, scale,
        (long)SEQ * 1536, (long)SEQ * 1536, (long)SEQ * SEQ);

    // PV split-K=2: partial[kc][b][row][col] = P'[:, kc*1024:+1024] @ vt^T
    gemm_k<2, true><<<dim3(4, 16, 8), 256, 0, stream>>>(
        Pb, vt, partial, nullptr, nullptr, 2048, 2048, 512, 32, 1.0f,
        (long)SEQ * SEQ, (long)DIM * SEQ, (long)SEQ * DIM);

    reduce_scale_k<<<4096, 256, 0, stream>>>(partial, rowsum, out);
}

// Round 4
// 190.063 us; speedup vs baseline: 1.0565x; 1.0471x over previous
//
#include <hip/hip_runtime.h>
#include <cstdint>
#include <cstddef>

#define SEQ 2048
#define DIM 512

using floatx4 = __attribute__((ext_vector_type(4))) float;
using halfx8  = __attribute__((ext_vector_type(8))) _Float16;

__device__ __forceinline__ ushort f2h(float f) {
    _Float16 h = (_Float16)f;
    return __builtin_bit_cast(unsigned short, h);
}

// ---------------- prep: x->fp16, W->fp16 cat, bias cat ----------------
// x: 1,048,576 float4 ; W: 196,608 float4 ; b: 384 float4
__global__ void prep_k(const float* __restrict__ x,
                       const float* __restrict__ Wq, const float* __restrict__ Wk,
                       const float* __restrict__ Wv,
                       const float* __restrict__ bq, const float* __restrict__ bk,
                       const float* __restrict__ bv,
                       ushort* __restrict__ xh, ushort* __restrict__ wcat,
                       float* __restrict__ bcat) {
    int i = blockIdx.x * 256 + threadIdx.x;
    if (i < 1048576) {
        float4 v = ((const float4*)x)[i];
        ((ushort4*)xh)[i] = make_ushort4(f2h(v.x), f2h(v.y), f2h(v.z), f2h(v.w));
    } else if (i < 1048576 + 196608) {
        int j = i - 1048576;
        int which = j >> 16;
        const float* w = (which == 0) ? Wq : (which == 1) ? Wk : Wv;
        float4 v = ((const float4*)w)[j & 0xFFFF];
        ((ushort4*)wcat)[j] = make_ushort4(f2h(v.x), f2h(v.y), f2h(v.z), f2h(v.w));
    } else if (i < 1048576 + 196608 + 384) {
        int j = i - 1245184;
        const float* bsrc = (j < 128) ? bq : (j < 256) ? bk : bv;
        ((float4*)bcat)[j] = ((const float4*)bsrc)[j & 127];
    }
}

// ---------------- pipelined NT GEMM, 128x128xBK32, fp16, LDS-coalesced epilogues ----
// EPI 0 = QKV: n0<1024 -> q/k fp16 to qkh (ld 1024) via Ps; n0>=1024 -> v scattered
//              transposed into vt[b][e][j] as 8B packs. +bias.
// EPI 1 = SCORES: P = exp(acc*alpha) fp16 via Ps coalesced; fp32 rowsum atomics.
// EPI 2 = PV split-K=4 partial: fp32 scatter store, slab = bz (kc*4+b).

template<int EPI>
__global__ __launch_bounds__(256, 3)
void gemm_k(const ushort* __restrict__ A, const ushort* __restrict__ B,
            void* __restrict__ Cout, const float* __restrict__ bias,
            float* __restrict__ rowsum, ushort* __restrict__ vt,
            int lda, int ldb, int ldc, int kIters, float alpha,
            long sA, long sB, long sC)
{
    __shared__ __align__(16) ushort smem[2][2][4096];  // As=smem[0][buf], Bs=smem[1][buf]; Ps aliases 32KB
    __shared__ float rsum[128];
    ushort* Ps = &smem[0][0][0];

    const int tid = threadIdx.x;
    const int bz = blockIdx.z;
    int b, kofs;
    if (EPI == 2) { b = bz & 3; kofs = (bz >> 2) * 512; }
    else          { b = bz; kofs = 0; }
    const ushort* Ab = A + (size_t)b * sA + kofs;
    const ushort* Bb = B + (size_t)b * sB + kofs;

    const int m0 = blockIdx.y * 128;
    const int n0 = blockIdx.x * 128;
    const int lane = tid & 63, wave = tid >> 6;
    const int wm = (wave >> 1) * 64, wn = (wave & 1) * 64;
    const int quad = lane >> 4, l16 = lane & 15;
    const int swz = (l16 >> 1) & 3;

    // staging: slot s holds global chunk (s&3) ^ ((row>>1)&3) of row s>>2
    const int s0 = tid, s1 = tid + 256;
    const int r0 = s0 >> 2, r1 = s1 >> 2;
    const int kc0 = (s0 & 3) ^ ((r0 >> 1) & 3);
    const int kc1 = (s1 & 3) ^ ((r1 >> 1) & 3);
    const ushort* gA0 = Ab + (size_t)(m0 + r0) * lda + kc0 * 8;
    const ushort* gA1 = Ab + (size_t)(m0 + r1) * lda + kc1 * 8;
    const ushort* gB0 = Bb + (size_t)(n0 + r0) * ldb + kc0 * 8;
    const ushort* gB1 = Bb + (size_t)(n0 + r1) * ldb + kc1 * 8;

#define STAGE(kk, bufi) do {                                                              \
    int ko = (kk) * 32;                                                                   \
    __builtin_amdgcn_global_load_lds((const __attribute__((address_space(1))) uint32_t*)(gA0 + ko), \
        (__attribute__((address_space(3))) uint32_t*)(&smem[0][bufi][s0 * 8]), 16, 0, 0); \
    __builtin_amdgcn_global_load_lds((const __attribute__((address_space(1))) uint32_t*)(gA1 + ko), \
        (__attribute__((address_space(3))) uint32_t*)(&smem[0][bufi][s1 * 8]), 16, 0, 0); \
    __builtin_amdgcn_global_load_lds((const __attribute__((address_space(1))) uint32_t*)(gB0 + ko), \
        (__attribute__((address_space(3))) uint32_t*)(&smem[1][bufi][s0 * 8]), 16, 0, 0); \
    __builtin_amdgcn_global_load_lds((const __attribute__((address_space(1))) uint32_t*)(gB1 + ko), \
        (__attribute__((address_space(3))) uint32_t*)(&smem[1][bufi][s1 * 8]), 16, 0, 0); \
} while (0)

    int ofsA[4], ofsB[4];
#pragma unroll
    for (int mi = 0; mi < 4; mi++)
        ofsA[mi] = ((wm + mi * 16 + l16) * 4 + (quad ^ swz)) * 8;
#pragma unroll
    for (int ni = 0; ni < 4; ni++)
        ofsB[ni] = ((wn + ni * 16 + l16) * 4 + (quad ^ swz)) * 8;

    floatx4 acc[4][4];
#pragma unroll
    for (int i = 0; i < 4; i++)
#pragma unroll
        for (int j = 0; j < 4; j++)
            acc[i][j] = (floatx4){0.f, 0.f, 0.f, 0.f};

    if (EPI == 1 && tid < 128) rsum[tid] = 0.f;

    STAGE(0, 0);
    for (int it = 0; it < kIters; ++it) {
        __syncthreads();
        const int buf = it & 1;
        if (it + 1 < kIters) STAGE(it + 1, buf ^ 1);
        halfx8 af[4], bfr[4];
#pragma unroll
        for (int mi = 0; mi < 4; mi++) af[mi] = *(const halfx8*)&smem[0][buf][ofsA[mi]];
#pragma unroll
        for (int ni = 0; ni < 4; ni++) bfr[ni] = *(const halfx8*)&smem[1][buf][ofsB[ni]];
#pragma unroll
        for (int mi = 0; mi < 4; mi++)
#pragma unroll
            for (int ni = 0; ni < 4; ni++)
                acc[mi][ni] = __builtin_amdgcn_mfma_f32_16x16x32_f16(af[mi], bfr[ni], acc[mi][ni], 0, 0, 0);
    }
#undef STAGE

    if constexpr (EPI == 2) {
        // fp32 partial scatter (quad-coalesced 64B segments)
#pragma unroll
        for (int mi = 0; mi < 4; mi++)
#pragma unroll
            for (int ni = 0; ni < 4; ni++) {
                int col = n0 + wn + ni * 16 + l16;
#pragma unroll
                for (int r = 0; r < 4; r++) {
                    int row = m0 + wm + mi * 16 + quad * 4 + r;
                    ((float*)Cout)[(size_t)bz * sC + (size_t)row * ldc + col] = acc[mi][ni][r];
                }
            }
    } else if (EPI == 0 && n0 >= 1024) {
        // v path: transpose into vt[b*512+e][j], 4 consecutive rows(j) pack to 8B
#pragma unroll
        for (int ni = 0; ni < 4; ni++) {
            int col = n0 + wn + ni * 16 + l16;
            float bv = bias[col];
            int e = col - 1024;
#pragma unroll
            for (int mi = 0; mi < 4; mi++) {
                int row0 = m0 + wm + mi * 16 + quad * 4;
                int bb = row0 >> 11;
                int j = row0 & 2047;
                ushort4 pk = make_ushort4(f2h(acc[mi][ni][0] + bv), f2h(acc[mi][ni][1] + bv),
                                          f2h(acc[mi][ni][2] + bv), f2h(acc[mi][ni][3] + bv));
                *(ushort4*)&vt[((size_t)(bb << 9) + e) * 2048 + j] = pk;
            }
        }
    } else {
        // Ps-coalesced path (EPI0 q/k with bias; EPI1 with exp + rowsum)
        float bvv[4];
        if (EPI == 0) {
#pragma unroll
            for (int ni = 0; ni < 4; ni++) bvv[ni] = bias[n0 + wn + ni * 16 + l16];
        }
        __syncthreads();   // staging reads finished everywhere before Ps overwrite
#pragma unroll
        for (int mi = 0; mi < 4; mi++)
#pragma unroll
            for (int ni = 0; ni < 4; ni++) {
                int col_l = wn + ni * 16 + l16;
                int c = col_l >> 3, w = col_l & 7;
#pragma unroll
                for (int r = 0; r < 4; r++) {
                    int row_l = wm + mi * 16 + quad * 4 + r;
                    float v = (EPI == 1) ? __expf(acc[mi][ni][r] * alpha)
                                         : acc[mi][ni][r] + bvv[ni];
                    Ps[row_l * 128 + ((c ^ (row_l & 7)) << 3) + w] = f2h(v);
                }
            }
        __syncthreads();
        // coalesced read-back: thread -> (row rr, half h)
        int rr = tid >> 1, h = tid & 1;
        float s = 0.f;
        size_t base = (EPI == 1) ? (size_t)b * sC : 0;
        ushort* dstrow = (ushort*)Cout + base + (size_t)(m0 + rr) * ldc + n0;
#pragma unroll
        for (int j = 0; j < 8; j++) {
            int c = h * 8 + j;
            halfx8 p = *(const halfx8*)&Ps[rr * 128 + ((c ^ (rr & 7)) << 3)];
            if (EPI == 1) {
#pragma unroll
                for (int e = 0; e < 8; e++) s += (float)p[e];
            }
            *(halfx8*)(dstrow + c * 8) = p;
        }
        if (EPI == 1) {
            atomicAdd(&rsum[rr], s);
            __syncthreads();
            if (tid < 128) atomicAdd(&rowsum[b * SEQ + m0 + tid], rsum[tid]);
        }
    }
}

// ---------------- reduce split-K=4 partials + softmax normalization ----------------
__global__ void reduce_scale_k(const float* __restrict__ part, const float* __restrict__ rowsum,
                               float* __restrict__ out) {
    int i = blockIdx.x * 256 + threadIdx.x;  // float4 index over out (1,048,576)
    int g = i >> 7;                           // global row 0..8191
    int b = g >> 11;
    int local = i - (b << 18);                // float4 within batch slab (1<<18 per batch)
    float4 a = {0.f, 0.f, 0.f, 0.f};
#pragma unroll
    for (int kc = 0; kc < 4; kc++) {
        const float4* p = (const float4*)part + ((size_t)(kc * 4 + b) << 18);
        float4 v = p[local];
        a.x += v.x; a.y += v.y; a.z += v.z; a.w += v.w;
    }
    float inv = 1.0f / rowsum[g];
    float4 o = {a.x * inv, a.y * inv, a.z * inv, a.w * inv};
    ((float4*)out)[i] = o;
}

// ---------------- launch ----------------
extern "C" void kernel_launch(void* const* d_in, const int* in_sizes, int n_in,
                              void* d_out, int out_size, void* d_ws, size_t ws_size,
                              hipStream_t stream) {
    const float* x  = (const float*)d_in[0];
    const float* Wq = (const float*)d_in[1];
    const float* bq = (const float*)d_in[2];
    const float* Wk = (const float*)d_in[3];
    const float* bk = (const float*)d_in[4];
    const float* Wv = (const float*)d_in[5];
    const float* bv = (const float*)d_in[6];
    float* out = (float*)d_out;
    char* ws = (char*)d_ws;

    // ws layout. partial (written by PV) overlays xh/wcat/bcat (dead after QKV).
    float*  partial = (float*)(ws);                 // 67,108,864 (16 slabs of 4 MB)
    ushort* xh      = (ushort*)(ws);                //  8,388,608 (alias, early phase)
    ushort* wcat    = (ushort*)(ws + 8388608);      //  1,572,864 (alias, early phase)
    float*  bcat    = (float*)(ws + 9961472);       //      6,144 (alias, early phase)
    float*  rowsum  = (float*)(ws + 67108864);      //     32,768
    ushort* Pb      = (ushort*)(ws + 67141632);     // 33,554,432 fp16 exp(s)
    ushort* vt      = (ushort*)(ws + 100696064);    //  8,388,608 fp16 v transposed
    ushort* qkh     = (ushort*)(ws + 109084672);    // 33,554,432 fp16 q|k, ld 1024
    // total 142,639,104

    hipMemsetAsync(rowsum, 0, 8192 * 4, stream);
    prep_k<<<4866, 256, 0, stream>>>(x, Wq, Wk, Wv, bq, bk, bv, xh, wcat, bcat);

    // QKV: q/k -> qkh [8192,1024]; v -> vt [4*512,2048] transposed. K=512.
    gemm_k<0><<<dim3(12, 64, 1), 256, 0, stream>>>(
        xh, wcat, qkh, bcat, nullptr, vt, 512, 512, 1024, 16, 1.0f, 0, 0, 0);

    // scores: P = exp(scale * q@k^T) fp16 [b][2048][2048], rowsum fp32
    const float scale = 0.04419417382415922f;  // 1/sqrt(512)
    gemm_k<1><<<dim3(16, 16, 4), 256, 0, stream>>>(
        qkh, qkh + 512, Pb, nullptr, rowsum, nullptr, 1024, 1024, 2048, 16, scale,
        (long)SEQ * 1024, (long)SEQ * 1024, (long)SEQ * SEQ);

    // PV split-K=4: partial[kc*4+b][2048][512] = P[:,kc*512:+512] @ vt^T
    gemm_k<2><<<dim3(4, 16, 16), 256, 0, stream>>>(
        Pb, vt, partial, nullptr, nullptr, nullptr, 2048, 2048, 512, 16, 1.0f,
        (long)SEQ * SEQ, (long)DIM * SEQ, (long)SEQ * DIM);

    reduce_scale_k<<<4096, 256, 0, stream>>>(partial, rowsum, out);
}

// Round 5
// 185.924 us; speedup vs baseline: 1.0801x; 1.0223x over previous
//
#include <hip/hip_runtime.h>
#include <cstdint>
#include <cstddef>

#define SEQ 2048
#define DIM 512

using floatx4 = __attribute__((ext_vector_type(4))) float;
using halfx8  = __attribute__((ext_vector_type(8))) _Float16;

__device__ __forceinline__ ushort f2h(float f) {
    _Float16 h = (_Float16)f;
    return __builtin_bit_cast(unsigned short, h);
}

// ---------------- prep: x->fp16, W->fp16 cat, bias cat, rowsum zero ----------------
// x: 1,048,576 float4 ; W: 196,608 float4 ; b: 384 float4 ; rowsum: 2048 float4
__global__ void prep_k(const float* __restrict__ x,
                       const float* __restrict__ Wq, const float* __restrict__ Wk,
                       const float* __restrict__ Wv,
                       const float* __restrict__ bq, const float* __restrict__ bk,
                       const float* __restrict__ bv,
                       ushort* __restrict__ xh, ushort* __restrict__ wcat,
                       float* __restrict__ bcat, float* __restrict__ rowsum) {
    int i = blockIdx.x * 256 + threadIdx.x;
    if (i < 1048576) {
        float4 v = ((const float4*)x)[i];
        ((ushort4*)xh)[i] = make_ushort4(f2h(v.x), f2h(v.y), f2h(v.z), f2h(v.w));
    } else if (i < 1048576 + 196608) {
        int j = i - 1048576;
        int which = j >> 16;
        const float* w = (which == 0) ? Wq : (which == 1) ? Wk : Wv;
        float4 v = ((const float4*)w)[j & 0xFFFF];
        ((ushort4*)wcat)[j] = make_ushort4(f2h(v.x), f2h(v.y), f2h(v.z), f2h(v.w));
    } else if (i < 1048576 + 196608 + 384) {
        int j = i - 1245184;
        const float* bsrc = (j < 128) ? bq : (j < 256) ? bk : bv;
        ((float4*)bcat)[j] = ((const float4*)bsrc)[j & 127];
    } else if (i < 1048576 + 196608 + 384 + 2048) {
        int j = i - 1245568;
        ((float4*)rowsum)[j] = (float4){0.f, 0.f, 0.f, 0.f};
    }
}

// ---------------- pipelined NT GEMM, 128x128xBK32, fp16, LDS-coalesced epilogues ----
// EPI 0 = QKV: n0<1024 -> q/k fp16 to qkh (ld 1024) via Ps; n0>=1024 -> v transposed
//              into vt[b][e][j] as 8B packs. +bias.
// EPI 1 = SCORES: P = exp(acc*alpha) fp16 via Ps; fp32 rowsum atomics.
// EPI 2 = PV split-K=4: NORMALIZED fp16 partial via Ps (acc * rcp(rowsum[row])).

template<int EPI>
__global__ __launch_bounds__(256, 4)
void gemm_k(const ushort* __restrict__ A, const ushort* __restrict__ B,
            void* __restrict__ Cout, const float* __restrict__ bias,
            float* __restrict__ rowsum, ushort* __restrict__ vt,
            int lda, int ldb, int ldc, int kIters, float alpha,
            long sA, long sB, long sC)
{
    __shared__ __align__(16) ushort smem[2][2][4096];  // As=smem[0][buf], Bs=smem[1][buf]; Ps aliases
    __shared__ float rsum[128];
    ushort* Ps = &smem[0][0][0];

    const int tid = threadIdx.x;
    const int bz = blockIdx.z;
    int b, kofs;
    if (EPI == 2) { b = bz & 3; kofs = (bz >> 2) * 512; }
    else          { b = bz; kofs = 0; }
    const ushort* Ab = A + (size_t)b * sA + kofs;
    const ushort* Bb = B + (size_t)b * sB + kofs;

    const int m0 = blockIdx.y * 128;
    const int n0 = blockIdx.x * 128;
    const int lane = tid & 63, wave = tid >> 6;
    const int wm = (wave >> 1) * 64, wn = (wave & 1) * 64;
    const int quad = lane >> 4, l16 = lane & 15;
    const int swz = (l16 >> 1) & 3;

    const int s0 = tid, s1 = tid + 256;
    const int r0 = s0 >> 2, r1 = s1 >> 2;
    const int kc0 = (s0 & 3) ^ ((r0 >> 1) & 3);
    const int kc1 = (s1 & 3) ^ ((r1 >> 1) & 3);
    const ushort* gA0 = Ab + (size_t)(m0 + r0) * lda + kc0 * 8;
    const ushort* gA1 = Ab + (size_t)(m0 + r1) * lda + kc1 * 8;
    const ushort* gB0 = Bb + (size_t)(n0 + r0) * ldb + kc0 * 8;
    const ushort* gB1 = Bb + (size_t)(n0 + r1) * ldb + kc1 * 8;

#define STAGE(kk, bufi) do {                                                              \
    int ko = (kk) * 32;                                                                   \
    __builtin_amdgcn_global_load_lds((const __attribute__((address_space(1))) uint32_t*)(gA0 + ko), \
        (__attribute__((address_space(3))) uint32_t*)(&smem[0][bufi][s0 * 8]), 16, 0, 0); \
    __builtin_amdgcn_global_load_lds((const __attribute__((address_space(1))) uint32_t*)(gA1 + ko), \
        (__attribute__((address_space(3))) uint32_t*)(&smem[0][bufi][s1 * 8]), 16, 0, 0); \
    __builtin_amdgcn_global_load_lds((const __attribute__((address_space(1))) uint32_t*)(gB0 + ko), \
        (__attribute__((address_space(3))) uint32_t*)(&smem[1][bufi][s0 * 8]), 16, 0, 0); \
    __builtin_amdgcn_global_load_lds((const __attribute__((address_space(1))) uint32_t*)(gB1 + ko), \
        (__attribute__((address_space(3))) uint32_t*)(&smem[1][bufi][s1 * 8]), 16, 0, 0); \
} while (0)

    int ofsA[4], ofsB[4];
#pragma unroll
    for (int mi = 0; mi < 4; mi++)
        ofsA[mi] = ((wm + mi * 16 + l16) * 4 + (quad ^ swz)) * 8;
#pragma unroll
    for (int ni = 0; ni < 4; ni++)
        ofsB[ni] = ((wn + ni * 16 + l16) * 4 + (quad ^ swz)) * 8;

    floatx4 acc[4][4];
#pragma unroll
    for (int i = 0; i < 4; i++)
#pragma unroll
        for (int j = 0; j < 4; j++)
            acc[i][j] = (floatx4){0.f, 0.f, 0.f, 0.f};

    if (EPI == 1 && tid < 128) rsum[tid] = 0.f;

    STAGE(0, 0);
    for (int it = 0; it < kIters; ++it) {
        __syncthreads();
        const int buf = it & 1;
        if (it + 1 < kIters) STAGE(it + 1, buf ^ 1);
        halfx8 af[4], bfr[4];
#pragma unroll
        for (int mi = 0; mi < 4; mi++) af[mi] = *(const halfx8*)&smem[0][buf][ofsA[mi]];
#pragma unroll
        for (int ni = 0; ni < 4; ni++) bfr[ni] = *(const halfx8*)&smem[1][buf][ofsB[ni]];
#pragma unroll
        for (int mi = 0; mi < 4; mi++)
#pragma unroll
            for (int ni = 0; ni < 4; ni++)
                acc[mi][ni] = __builtin_amdgcn_mfma_f32_16x16x32_f16(af[mi], bfr[ni], acc[mi][ni], 0, 0, 0);
    }
#undef STAGE

    if (EPI == 0 && n0 >= 1024) {
        // v path: transpose into vt[b*512+e][j], 4 consecutive rows(j) pack to 8B
#pragma unroll
        for (int ni = 0; ni < 4; ni++) {
            int col = n0 + wn + ni * 16 + l16;
            float bv = bias[col];
            int e = col - 1024;
#pragma unroll
            for (int mi = 0; mi < 4; mi++) {
                int row0 = m0 + wm + mi * 16 + quad * 4;
                int bb = row0 >> 11;
                int j = row0 & 2047;
                ushort4 pk = make_ushort4(f2h(acc[mi][ni][0] + bv), f2h(acc[mi][ni][1] + bv),
                                          f2h(acc[mi][ni][2] + bv), f2h(acc[mi][ni][3] + bv));
                *(ushort4*)&vt[((size_t)(bb << 9) + e) * 2048 + j] = pk;
            }
        }
    } else {
        // Ps-coalesced path: EPI0 q/k (+bias), EPI1 (exp + rowsum), EPI2 (normalize)
        float bvv[4];
        if (EPI == 0) {
#pragma unroll
            for (int ni = 0; ni < 4; ni++) bvv[ni] = bias[n0 + wn + ni * 16 + l16];
        }
        float inv[4][4];
        if (EPI == 2) {
#pragma unroll
            for (int mi = 0; mi < 4; mi++)
#pragma unroll
                for (int r = 0; r < 4; r++)
                    inv[mi][r] = __builtin_amdgcn_rcpf(
                        rowsum[b * SEQ + m0 + wm + mi * 16 + quad * 4 + r]);
        }
        __syncthreads();   // staging reads finished everywhere before Ps overwrite
#pragma unroll
        for (int mi = 0; mi < 4; mi++)
#pragma unroll
            for (int ni = 0; ni < 4; ni++) {
                int col_l = wn + ni * 16 + l16;
                int c = col_l >> 3, w = col_l & 7;
#pragma unroll
                for (int r = 0; r < 4; r++) {
                    int row_l = wm + mi * 16 + quad * 4 + r;
                    float v = (EPI == 1) ? __expf(acc[mi][ni][r] * alpha)
                            : (EPI == 2) ? acc[mi][ni][r] * inv[mi][r]
                                         : acc[mi][ni][r] + bvv[ni];
                    Ps[row_l * 128 + ((c ^ (row_l & 7)) << 3) + w] = f2h(v);
                }
            }
        __syncthreads();
        // coalesced read-back: thread -> (row rr, half h)
        int rr = tid >> 1, h = tid & 1;
        float s = 0.f;
        size_t base = (EPI == 1) ? (size_t)b * sC : (EPI == 2) ? (size_t)bz * sC : 0;
        ushort* dstrow = (ushort*)Cout + base + (size_t)(m0 + rr) * ldc + n0;
#pragma unroll
        for (int j = 0; j < 8; j++) {
            int c = h * 8 + j;
            halfx8 p = *(const halfx8*)&Ps[rr * 128 + ((c ^ (rr & 7)) << 3)];
            if (EPI == 1) {
#pragma unroll
                for (int e = 0; e < 8; e++) s += (float)p[e];
            }
            *(halfx8*)(dstrow + c * 8) = p;
        }
        if (EPI == 1) {
            atomicAdd(&rsum[rr], s);
            __syncthreads();
            if (tid < 128) atomicAdd(&rowsum[b * SEQ + m0 + tid], rsum[tid]);
        }
    }
}

// ---------------- sum 4 normalized fp16 split-K partials -> fp32 out ----------------
__global__ void reduce_k(const ushort* __restrict__ part, float* __restrict__ out) {
    int t = blockIdx.x * 256 + threadIdx.x;   // each handles 8 elems; 524,288 threads
    size_t E = (size_t)t * 8;
    int b = (int)(E >> 20);                   // 2048*512 elems per batch
    size_t le = E & ((1u << 20) - 1);
    float acc[8] = {0,0,0,0,0,0,0,0};
#pragma unroll
    for (int kc = 0; kc < 4; kc++) {
        halfx8 p = *(const halfx8*)&part[(((size_t)(kc * 4 + b)) << 20) + le];
#pragma unroll
        for (int e = 0; e < 8; e++) acc[e] += (float)p[e];
    }
    float4 o0 = {acc[0], acc[1], acc[2], acc[3]};
    float4 o1 = {acc[4], acc[5], acc[6], acc[7]};
    ((float4*)(out + E))[0] = o0;
    ((float4*)(out + E))[1] = o1;
}

// ---------------- launch ----------------
extern "C" void kernel_launch(void* const* d_in, const int* in_sizes, int n_in,
                              void* d_out, int out_size, void* d_ws, size_t ws_size,
                              hipStream_t stream) {
    const float* x  = (const float*)d_in[0];
    const float* Wq = (const float*)d_in[1];
    const float* bq = (const float*)d_in[2];
    const float* Wk = (const float*)d_in[3];
    const float* bk = (const float*)d_in[4];
    const float* Wv = (const float*)d_in[5];
    const float* bv = (const float*)d_in[6];
    float* out = (float*)d_out;
    char* ws = (char*)d_ws;

    // ws layout. partial (fp16, written by PV) overlays xh/wcat/bcat (dead after QKV).
    ushort* partial = (ushort*)(ws);                // 33,554,432 (16 slabs fp16 [2048][512])
    ushort* xh      = (ushort*)(ws);                //  8,388,608 (alias, early phase)
    ushort* wcat    = (ushort*)(ws + 8388608);      //  1,572,864 (alias, early phase)
    float*  bcat    = (float*)(ws + 9961472);       //      6,144 (alias, early phase)
    float*  rowsum  = (float*)(ws + 33554432);      //     32,768
    ushort* Pb      = (ushort*)(ws + 33587200);     // 33,554,432 fp16 exp(s)
    ushort* vt      = (ushort*)(ws + 67141632);     //  8,388,608 fp16 v transposed
    ushort* qkh     = (ushort*)(ws + 75530240);     // 33,554,432 fp16 q|k, ld 1024
    // total 109,084,672

    prep_k<<<4874, 256, 0, stream>>>(x, Wq, Wk, Wv, bq, bk, bv, xh, wcat, bcat, rowsum);

    // QKV: q/k -> qkh [8192,1024]; v -> vt [4*512,2048] transposed. K=512.
    gemm_k<0><<<dim3(12, 64, 1), 256, 0, stream>>>(
        xh, wcat, qkh, bcat, nullptr, vt, 512, 512, 1024, 16, 1.0f, 0, 0, 0);

    // scores: P = exp(scale * q@k^T) fp16 [b][2048][2048], rowsum fp32
    const float scale = 0.04419417382415922f;  // 1/sqrt(512)
    gemm_k<1><<<dim3(16, 16, 4), 256, 0, stream>>>(
        qkh, qkh + 512, Pb, nullptr, rowsum, nullptr, 1024, 1024, 2048, 16, scale,
        (long)SEQ * 1024, (long)SEQ * 1024, (long)SEQ * SEQ);

    // PV split-K=4: partial[kc*4+b][2048][512] = (P[:,kc*512:+512] @ vt^T) / rowsum
    gemm_k<2><<<dim3(4, 16, 16), 256, 0, stream>>>(
        Pb, vt, partial, nullptr, rowsum, nullptr, 2048, 2048, 512, 16, 1.0f,
        (long)SEQ * SEQ, (long)DIM * SEQ, (long)SEQ * DIM);

    reduce_k<<<2048, 256, 0, stream>>>(partial, out);
}

// Round 6
// 185.182 us; speedup vs baseline: 1.0844x; 1.0040x over previous
//
#include <hip/hip_runtime.h>
#include <cstdint>
#include <cstddef>

#define SEQ 2048
#define DIM 512

using floatx4 = __attribute__((ext_vector_type(4))) float;
using halfx8  = __attribute__((ext_vector_type(8))) _Float16;

__device__ __forceinline__ ushort f2h(float f) {
    _Float16 h = (_Float16)f;
    return __builtin_bit_cast(unsigned short, h);
}

// ---------------- prep: x->fp16, W->fp16 cat, bias cat, rowsum zero ----------------
__global__ void prep_k(const float* __restrict__ x,
                       const float* __restrict__ Wq, const float* __restrict__ Wk,
                       const float* __restrict__ Wv,
                       const float* __restrict__ bq, const float* __restrict__ bk,
                       const float* __restrict__ bv,
                       ushort* __restrict__ xh, ushort* __restrict__ wcat,
                       float* __restrict__ bcat, float* __restrict__ rowsum) {
    int i = blockIdx.x * 256 + threadIdx.x;
    if (i < 1048576) {
        float4 v = ((const float4*)x)[i];
        ((ushort4*)xh)[i] = make_ushort4(f2h(v.x), f2h(v.y), f2h(v.z), f2h(v.w));
    } else if (i < 1048576 + 196608) {
        int j = i - 1048576;
        int which = j >> 16;
        const float* w = (which == 0) ? Wq : (which == 1) ? Wk : Wv;
        float4 v = ((const float4*)w)[j & 0xFFFF];
        ((ushort4*)wcat)[j] = make_ushort4(f2h(v.x), f2h(v.y), f2h(v.z), f2h(v.w));
    } else if (i < 1048576 + 196608 + 384) {
        int j = i - 1245184;
        const float* bsrc = (j < 128) ? bq : (j < 256) ? bk : bv;
        ((float4*)bcat)[j] = ((const float4*)bsrc)[j & 127];
    } else if (i < 1048576 + 196608 + 384 + 2048) {
        int j = i - 1245568;
        ((float4*)rowsum)[j] = (float4){0.f, 0.f, 0.f, 0.f};
    }
}

// ------- depth-2 pipelined NT GEMM, 128x128xBK32, fp16, 3 LDS buffer sets ----------
// Per iter: s_waitcnt vmcnt(4) + raw s_barrier (newest stage stays in flight across
// the barrier — FIFO vmcnt waits only the oldest stage, issued 2 iters ago).
// EPI 0 = QKV: n0<1024 -> q/k via Ps coalesced (+bias); n0>=1024 -> v transposed to vt.
// EPI 1 = SCORES: P = exp(acc*alpha) fp16 via Ps; fp32 rowsum atomics.
// EPI 2 = PV split-K=4: normalized fp16 partial via Ps (acc * rcp(rowsum[row])).

template<int EPI>
__global__ __launch_bounds__(256, 3)
void gemm_k(const ushort* __restrict__ A, const ushort* __restrict__ B,
            void* __restrict__ Cout, const float* __restrict__ bias,
            float* __restrict__ rowsum, ushort* __restrict__ vt,
            int lda, int ldb, int ldc, int kIters, float alpha,
            long sA, long sB, long sC)
{
    // smem[buf][0]=A tile, smem[buf][1]=B tile; Ps (32 KB) aliases smem[0..1][*]
    __shared__ __align__(16) ushort smem[3][2][4096];
    __shared__ float rsum[128];
    ushort* Ps = &smem[0][0][0];

    const int tid = threadIdx.x;
    const int bz = blockIdx.z;
    int b, kofs;
    if (EPI == 2) { b = bz & 3; kofs = (bz >> 2) * 512; }
    else          { b = bz; kofs = 0; }
    const ushort* Ab = A + (size_t)b * sA + kofs;
    const ushort* Bb = B + (size_t)b * sB + kofs;

    const int m0 = blockIdx.y * 128;
    const int n0 = blockIdx.x * 128;
    const int lane = tid & 63, wave = tid >> 6;
    const int wm = (wave >> 1) * 64, wn = (wave & 1) * 64;
    const int quad = lane >> 4, l16 = lane & 15;
    const int swz = (l16 >> 1) & 3;

    const int s0 = tid, s1 = tid + 256;
    const int r0 = s0 >> 2, r1 = s1 >> 2;
    const int kc0 = (s0 & 3) ^ ((r0 >> 1) & 3);
    const int kc1 = (s1 & 3) ^ ((r1 >> 1) & 3);
    const ushort* gA0 = Ab + (size_t)(m0 + r0) * lda + kc0 * 8;
    const ushort* gA1 = Ab + (size_t)(m0 + r1) * lda + kc1 * 8;
    const ushort* gB0 = Bb + (size_t)(n0 + r0) * ldb + kc0 * 8;
    const ushort* gB1 = Bb + (size_t)(n0 + r1) * ldb + kc1 * 8;

#define STAGE(kk, bufi) do {                                                              \
    int ko = (kk) * 32;                                                                   \
    __builtin_amdgcn_global_load_lds((const __attribute__((address_space(1))) uint32_t*)(gA0 + ko), \
        (__attribute__((address_space(3))) uint32_t*)(&smem[bufi][0][s0 * 8]), 16, 0, 0); \
    __builtin_amdgcn_global_load_lds((const __attribute__((address_space(1))) uint32_t*)(gA1 + ko), \
        (__attribute__((address_space(3))) uint32_t*)(&smem[bufi][0][s1 * 8]), 16, 0, 0); \
    __builtin_amdgcn_global_load_lds((const __attribute__((address_space(1))) uint32_t*)(gB0 + ko), \
        (__attribute__((address_space(3))) uint32_t*)(&smem[bufi][1][s0 * 8]), 16, 0, 0); \
    __builtin_amdgcn_global_load_lds((const __attribute__((address_space(1))) uint32_t*)(gB1 + ko), \
        (__attribute__((address_space(3))) uint32_t*)(&smem[bufi][1][s1 * 8]), 16, 0, 0); \
} while (0)

    int ofsA[4], ofsB[4];
#pragma unroll
    for (int mi = 0; mi < 4; mi++)
        ofsA[mi] = ((wm + mi * 16 + l16) * 4 + (quad ^ swz)) * 8;
#pragma unroll
    for (int ni = 0; ni < 4; ni++)
        ofsB[ni] = ((wn + ni * 16 + l16) * 4 + (quad ^ swz)) * 8;

    floatx4 acc[4][4];
#pragma unroll
    for (int i = 0; i < 4; i++)
#pragma unroll
        for (int j = 0; j < 4; j++)
            acc[i][j] = (floatx4){0.f, 0.f, 0.f, 0.f};

    if (EPI == 1 && tid < 128) rsum[tid] = 0.f;

    STAGE(0, 0);
    STAGE(1, 1);
    for (int it = 0; it < kIters; ++it) {
        const int buf = it % 3;
        if (it + 1 < kIters) {
            // oldest in-flight stage (buf 'it') lands; newest stays in flight
            asm volatile("s_waitcnt vmcnt(4)\n\ts_barrier" ::: "memory");
        } else {
            asm volatile("s_waitcnt vmcnt(0)\n\ts_barrier" ::: "memory");
        }
        if (it + 2 < kIters) STAGE(it + 2, (it + 2) % 3);
        halfx8 af[4], bfr[4];
#pragma unroll
        for (int mi = 0; mi < 4; mi++) af[mi] = *(const halfx8*)&smem[buf][0][ofsA[mi]];
#pragma unroll
        for (int ni = 0; ni < 4; ni++) bfr[ni] = *(const halfx8*)&smem[buf][1][ofsB[ni]];
#pragma unroll
        for (int mi = 0; mi < 4; mi++)
#pragma unroll
            for (int ni = 0; ni < 4; ni++)
                acc[mi][ni] = __builtin_amdgcn_mfma_f32_16x16x32_f16(af[mi], bfr[ni], acc[mi][ni], 0, 0, 0);
    }
#undef STAGE

    if (EPI == 0 && n0 >= 1024) {
        // v path: transpose into vt[b*512+e][j], 4 consecutive rows(j) pack to 8B
#pragma unroll
        for (int ni = 0; ni < 4; ni++) {
            int col = n0 + wn + ni * 16 + l16;
            float bv = bias[col];
            int e = col - 1024;
#pragma unroll
            for (int mi = 0; mi < 4; mi++) {
                int row0 = m0 + wm + mi * 16 + quad * 4;
                int bb = row0 >> 11;
                int j = row0 & 2047;
                ushort4 pk = make_ushort4(f2h(acc[mi][ni][0] + bv), f2h(acc[mi][ni][1] + bv),
                                          f2h(acc[mi][ni][2] + bv), f2h(acc[mi][ni][3] + bv));
                *(ushort4*)&vt[((size_t)(bb << 9) + e) * 2048 + j] = pk;
            }
        }
    } else {
        // Ps-coalesced path: EPI0 q/k (+bias), EPI1 (exp + rowsum), EPI2 (normalize)
        float bvv[4];
        if (EPI == 0) {
#pragma unroll
            for (int ni = 0; ni < 4; ni++) bvv[ni] = bias[n0 + wn + ni * 16 + l16];
        }
        float inv[4][4];
        if (EPI == 2) {
#pragma unroll
            for (int mi = 0; mi < 4; mi++)
#pragma unroll
                for (int r = 0; r < 4; r++)
                    inv[mi][r] = __builtin_amdgcn_rcpf(
                        rowsum[b * SEQ + m0 + wm + mi * 16 + quad * 4 + r]);
        }
        __syncthreads();   // all waves done with staging LDS before Ps overwrite
#pragma unroll
        for (int mi = 0; mi < 4; mi++)
#pragma unroll
            for (int ni = 0; ni < 4; ni++) {
                int col_l = wn + ni * 16 + l16;
                int c = col_l >> 3, w = col_l & 7;
#pragma unroll
                for (int r = 0; r < 4; r++) {
                    int row_l = wm + mi * 16 + quad * 4 + r;
                    float v = (EPI == 1) ? __expf(acc[mi][ni][r] * alpha)
                            : (EPI == 2) ? acc[mi][ni][r] * inv[mi][r]
                                         : acc[mi][ni][r] + bvv[ni];
                    Ps[row_l * 128 + ((c ^ (row_l & 7)) << 3) + w] = f2h(v);
                }
            }
        __syncthreads();
        // coalesced read-back: thread -> (row rr, half h)
        int rr = tid >> 1, h = tid & 1;
        float s = 0.f;
        size_t base = (EPI == 1) ? (size_t)b * sC : (EPI == 2) ? (size_t)bz * sC : 0;
        ushort* dstrow = (ushort*)Cout + base + (size_t)(m0 + rr) * ldc + n0;
#pragma unroll
        for (int j = 0; j < 8; j++) {
            int c = h * 8 + j;
            halfx8 p = *(const halfx8*)&Ps[rr * 128 + ((c ^ (rr & 7)) << 3)];
            if (EPI == 1) {
#pragma unroll
                for (int e = 0; e < 8; e++) s += (float)p[e];
            }
            *(halfx8*)(dstrow + c * 8) = p;
        }
        if (EPI == 1) {
            atomicAdd(&rsum[rr], s);
            __syncthreads();
            if (tid < 128) atomicAdd(&rowsum[b * SEQ + m0 + tid], rsum[tid]);
        }
    }
}

// ---------------- sum 4 normalized fp16 split-K partials -> fp32 out ----------------
__global__ void reduce_k(const ushort* __restrict__ part, float* __restrict__ out) {
    int t = blockIdx.x * 256 + threadIdx.x;
    size_t E = (size_t)t * 8;
    int b = (int)(E >> 20);
    size_t le = E & ((1u << 20) - 1);
    float acc[8] = {0,0,0,0,0,0,0,0};
#pragma unroll
    for (int kc = 0; kc < 4; kc++) {
        halfx8 p = *(const halfx8*)&part[(((size_t)(kc * 4 + b)) << 20) + le];
#pragma unroll
        for (int e = 0; e < 8; e++) acc[e] += (float)p[e];
    }
    float4 o0 = {acc[0], acc[1], acc[2], acc[3]};
    float4 o1 = {acc[4], acc[5], acc[6], acc[7]};
    ((float4*)(out + E))[0] = o0;
    ((float4*)(out + E))[1] = o1;
}

// ---------------- launch ----------------
extern "C" void kernel_launch(void* const* d_in, const int* in_sizes, int n_in,
                              void* d_out, int out_size, void* d_ws, size_t ws_size,
                              hipStream_t stream) {
    const float* x  = (const float*)d_in[0];
    const float* Wq = (const float*)d_in[1];
    const float* bq = (const float*)d_in[2];
    const float* Wk = (const float*)d_in[3];
    const float* bk = (const float*)d_in[4];
    const float* Wv = (const float*)d_in[5];
    const float* bv = (const float*)d_in[6];
    float* out = (float*)d_out;
    char* ws = (char*)d_ws;

    // ws layout. partial (fp16, written by PV) overlays xh/wcat/bcat (dead after QKV).
    ushort* partial = (ushort*)(ws);                // 33,554,432 (16 slabs fp16 [2048][512])
    ushort* xh      = (ushort*)(ws);                //  8,388,608 (alias, early phase)
    ushort* wcat    = (ushort*)(ws + 8388608);      //  1,572,864 (alias, early phase)
    float*  bcat    = (float*)(ws + 9961472);       //      6,144 (alias, early phase)
    float*  rowsum  = (float*)(ws + 33554432);      //     32,768
    ushort* Pb      = (ushort*)(ws + 33587200);     // 33,554,432 fp16 exp(s)
    ushort* vt      = (ushort*)(ws + 67141632);     //  8,388,608 fp16 v transposed
    ushort* qkh     = (ushort*)(ws + 75530240);     // 33,554,432 fp16 q|k, ld 1024
    // total 109,084,672

    prep_k<<<4874, 256, 0, stream>>>(x, Wq, Wk, Wv, bq, bk, bv, xh, wcat, bcat, rowsum);

    // QKV: q/k -> qkh [8192,1024]; v -> vt [4*512,2048] transposed. K=512.
    gemm_k<0><<<dim3(12, 64, 1), 256, 0, stream>>>(
        xh, wcat, qkh, bcat, nullptr, vt, 512, 512, 1024, 16, 1.0f, 0, 0, 0);

    // scores: P = exp(scale * q@k^T) fp16 [b][2048][2048], rowsum fp32
    const float scale = 0.04419417382415922f;  // 1/sqrt(512)
    gemm_k<1><<<dim3(16, 16, 4), 256, 0, stream>>>(
        qkh, qkh + 512, Pb, nullptr, rowsum, nullptr, 1024, 1024, 2048, 16, scale,
        (long)SEQ * 1024, (long)SEQ * 1024, (long)SEQ * SEQ);

    // PV split-K=4: partial[kc*4+b][2048][512] = (P[:,kc*512:+512] @ vt^T) / rowsum
    gemm_k<2><<<dim3(4, 16, 16), 256, 0, stream>>>(
        Pb, vt, partial, nullptr, rowsum, nullptr, 2048, 2048, 512, 16, 1.0f,
        (long)SEQ * SEQ, (long)DIM * SEQ, (long)SEQ * DIM);

    reduce_k<<<2048, 256, 0, stream>>>(partial, out);
}

// Round 8
// 178.203 us; speedup vs baseline: 1.1269x; 1.0392x over previous
//
#include <hip/hip_runtime.h>
#include <cstdint>
#include <cstddef>

#define SEQ 2048
#define DIM 512

using floatx4 = __attribute__((ext_vector_type(4))) float;
using halfx8  = __attribute__((ext_vector_type(8))) _Float16;

__device__ __forceinline__ ushort f2h(float f) {
    _Float16 h = (_Float16)f;
    return __builtin_bit_cast(unsigned short, h);
}

// ---------------- prep: x->fp16, W->fp16 cat, bias cat, rowsum zero ----------------
__global__ void prep_k(const float* __restrict__ x,
                       const float* __restrict__ Wq, const float* __restrict__ Wk,
                       const float* __restrict__ Wv,
                       const float* __restrict__ bq, const float* __restrict__ bk,
                       const float* __restrict__ bv,
                       ushort* __restrict__ xh, ushort* __restrict__ wcat,
                       float* __restrict__ bcat, float* __restrict__ rowsum) {
    int i = blockIdx.x * 256 + threadIdx.x;
    if (i < 1048576) {
        float4 v = ((const float4*)x)[i];
        ((ushort4*)xh)[i] = make_ushort4(f2h(v.x), f2h(v.y), f2h(v.z), f2h(v.w));
    } else if (i < 1048576 + 196608) {
        int j = i - 1048576;
        int which = j >> 16;
        const float* w = (which == 0) ? Wq : (which == 1) ? Wk : Wv;
        float4 v = ((const float4*)w)[j & 0xFFFF];
        ((ushort4*)wcat)[j] = make_ushort4(f2h(v.x), f2h(v.y), f2h(v.z), f2h(v.w));
    } else if (i < 1048576 + 196608 + 384) {
        int j = i - 1245184;
        const float* bsrc = (j < 128) ? bq : (j < 256) ? bk : bv;
        ((float4*)bcat)[j] = ((const float4*)bsrc)[j & 127];
    } else if (i < 1048576 + 196608 + 384 + 2048) {
        int j = i - 1245568;
        ((float4*)rowsum)[j] = (float4){0.f, 0.f, 0.f, 0.f};
    }
}

// ------- NT GEMM, 256x128xBK32 tile, 512 threads (8 waves, 4x2 of 64x64) -----------
// Double-buffered LDS (A 2x16KB, B 2x8KB = 48KB). Ps (32KB) aliases As for epilogue.
// EPI 0 = QKV: n0<1024 -> q/k via Ps 2-pass (+bias); n0>=1024 -> v transposed to vt.
// EPI 1 = SCORES: P = exp(acc*alpha) fp16 via Ps 2-pass; rowsum via shfl + atomics.
// EPI 2 = PV split-K=4: normalized fp16 partial via Ps 2-pass (acc * rcp(rowsum)).

template<int EPI>
__global__ __launch_bounds__(512, 4)
void gemm_k(const ushort* __restrict__ A, const ushort* __restrict__ B,
            void* __restrict__ Cout, const float* __restrict__ bias,
            float* __restrict__ rowsum, ushort* __restrict__ vt,
            int lda, int ldb, int ldc, int kIters, float alpha,
            long sA, long sB, long sC)
{
    __shared__ __align__(16) ushort As[2][8192];   // 256x32 per buf
    __shared__ __align__(16) ushort Bs[2][4096];   // 128x32 per buf
    ushort* Ps = &As[0][0];                        // 32 KB epilogue staging

    const int tid = threadIdx.x;
    const int bz = blockIdx.z;
    int b, kofs;
    if (EPI == 2) { b = bz & 3; kofs = (bz >> 2) * 512; }
    else          { b = bz; kofs = 0; }
    const ushort* Ab = A + (size_t)b * sA + kofs;
    const ushort* Bb = B + (size_t)b * sB + kofs;

    const int m0 = blockIdx.y * 256;
    const int n0 = blockIdx.x * 128;
    const int lane = tid & 63, wave = tid >> 6;    // 8 waves
    const int wm = (wave >> 1) * 64, wn = (wave & 1) * 64;   // 4x2 grid
    const int quad = lane >> 4, l16 = lane & 15;
    const int swz = (l16 >> 1) & 3;

    // staging slots: A has 1024 slots (2/thread), B has 512 (1/thread)
    const int sA0 = tid, sA1 = tid + 512, sBs = tid;
    const int rA0 = sA0 >> 2, rA1 = sA1 >> 2, rB = sBs >> 2;
    const int kA0 = (sA0 & 3) ^ ((rA0 >> 1) & 3);
    const int kA1 = (sA1 & 3) ^ ((rA1 >> 1) & 3);
    const int kB  = (sBs & 3) ^ ((rB  >> 1) & 3);
    const ushort* gA0 = Ab + (size_t)(m0 + rA0) * lda + kA0 * 8;
    const ushort* gA1 = Ab + (size_t)(m0 + rA1) * lda + kA1 * 8;
    const ushort* gB0 = Bb + (size_t)(n0 + rB) * ldb + kB * 8;

#define STAGE(kk, bufi) do {                                                              \
    int ko = (kk) * 32;                                                                   \
    __builtin_amdgcn_global_load_lds((const __attribute__((address_space(1))) uint32_t*)(gA0 + ko), \
        (__attribute__((address_space(3))) uint32_t*)(&As[bufi][sA0 * 8]), 16, 0, 0);     \
    __builtin_amdgcn_global_load_lds((const __attribute__((address_space(1))) uint32_t*)(gA1 + ko), \
        (__attribute__((address_space(3))) uint32_t*)(&As[bufi][sA1 * 8]), 16, 0, 0);     \
    __builtin_amdgcn_global_load_lds((const __attribute__((address_space(1))) uint32_t*)(gB0 + ko), \
        (__attribute__((address_space(3))) uint32_t*)(&Bs[bufi][sBs * 8]), 16, 0, 0);     \
} while (0)

    int ofsA[4], ofsB[4];
#pragma unroll
    for (int mi = 0; mi < 4; mi++)
        ofsA[mi] = ((wm + mi * 16 + l16) * 4 + (quad ^ swz)) * 8;
#pragma unroll
    for (int ni = 0; ni < 4; ni++)
        ofsB[ni] = ((wn + ni * 16 + l16) * 4 + (quad ^ swz)) * 8;

    floatx4 acc[4][4];
#pragma unroll
    for (int i = 0; i < 4; i++)
#pragma unroll
        for (int j = 0; j < 4; j++)
            acc[i][j] = (floatx4){0.f, 0.f, 0.f, 0.f};

    STAGE(0, 0);
    for (int it = 0; it < kIters; ++it) {
        __syncthreads();
        const int buf = it & 1;
        if (it + 1 < kIters) STAGE(it + 1, buf ^ 1);
        halfx8 af[4], bfr[4];
#pragma unroll
        for (int mi = 0; mi < 4; mi++) af[mi] = *(const halfx8*)&As[buf][ofsA[mi]];
#pragma unroll
        for (int ni = 0; ni < 4; ni++) bfr[ni] = *(const halfx8*)&Bs[buf][ofsB[ni]];
#pragma unroll
        for (int mi = 0; mi < 4; mi++)
#pragma unroll
            for (int ni = 0; ni < 4; ni++)
                acc[mi][ni] = __builtin_amdgcn_mfma_f32_16x16x32_f16(af[mi], bfr[ni], acc[mi][ni], 0, 0, 0);
    }
#undef STAGE

    if (EPI == 0 && n0 >= 1024) {
        // v path: transpose into vt[b*512+e][j], 4 consecutive rows(j) pack to 8B
#pragma unroll
        for (int ni = 0; ni < 4; ni++) {
            int col = n0 + wn + ni * 16 + l16;
            float bv = bias[col];
            int e = col - 1024;
#pragma unroll
            for (int mi = 0; mi < 4; mi++) {
                int row0 = m0 + wm + mi * 16 + quad * 4;
                int bb = row0 >> 11;
                int j = row0 & 2047;
                ushort4 pk = make_ushort4(f2h(acc[mi][ni][0] + bv), f2h(acc[mi][ni][1] + bv),
                                          f2h(acc[mi][ni][2] + bv), f2h(acc[mi][ni][3] + bv));
                *(ushort4*)&vt[((size_t)(bb << 9) + e) * 2048 + j] = pk;
            }
        }
    } else {
        // Ps-coalesced 2-pass epilogue (128 rows per pass)
        float bvv[4];
        if (EPI == 0) {
#pragma unroll
            for (int ni = 0; ni < 4; ni++) bvv[ni] = bias[n0 + wn + ni * 16 + l16];
        }
        float inv[4][4];
        if (EPI == 2) {
#pragma unroll
            for (int mi = 0; mi < 4; mi++)
#pragma unroll
                for (int r = 0; r < 4; r++)
                    inv[mi][r] = __builtin_amdgcn_rcpf(
                        rowsum[b * SEQ + m0 + wm + mi * 16 + quad * 4 + r]);
        }
        size_t base = (EPI == 1) ? (size_t)b * sC : (EPI == 2) ? (size_t)bz * sC : 0;
        __syncthreads();   // all waves done with staging LDS before Ps overwrite
#pragma unroll
        for (int p = 0; p < 2; ++p) {
            if ((wm >> 7) == p) {
                int wml = wm & 127;  // 0 or 64 within the 128-row pass
#pragma unroll
                for (int mi = 0; mi < 4; mi++)
#pragma unroll
                    for (int ni = 0; ni < 4; ni++) {
                        int col_l = wn + ni * 16 + l16;
                        int c = col_l >> 3, w = col_l & 7;
#pragma unroll
                        for (int r = 0; r < 4; r++) {
                            int row_l = wml + mi * 16 + quad * 4 + r;
                            float v = (EPI == 1) ? __expf(acc[mi][ni][r] * alpha)
                                    : (EPI == 2) ? acc[mi][ni][r] * inv[mi][r]
                                                 : acc[mi][ni][r] + bvv[ni];
                            Ps[row_l * 128 + ((c ^ (row_l & 7)) << 3) + w] = f2h(v);
                        }
                    }
            }
            __syncthreads();
            // readback: 512 threads cover 128 rows x 16 chunks
            int rr = tid >> 2, t3 = tid & 3;
            float s = 0.f;
            ushort* dstrow = (ushort*)Cout + base + (size_t)(m0 + p * 128 + rr) * ldc + n0;
#pragma unroll
            for (int j = 0; j < 4; j++) {
                int c = j * 4 + t3;
                halfx8 pv = *(const halfx8*)&Ps[rr * 128 + ((c ^ (rr & 7)) << 3)];
                if (EPI == 1) {
#pragma unroll
                    for (int e = 0; e < 8; e++) s += (float)pv[e];
                }
                *(halfx8*)(dstrow + c * 8) = pv;
            }
            if (EPI == 1) {
                s += __shfl_xor(s, 1);
                s += __shfl_xor(s, 2);
                if (t3 == 0) atomicAdd(&rowsum[b * SEQ + m0 + p * 128 + rr], s);
            }
            __syncthreads();
        }
    }
}

// ---------------- sum 4 normalized fp16 split-K partials -> fp32 out ----------------
__global__ void reduce_k(const ushort* __restrict__ part, float* __restrict__ out) {
    int t = blockIdx.x * 256 + threadIdx.x;
    size_t E = (size_t)t * 8;
    int b = (int)(E >> 20);
    size_t le = E & ((1u << 20) - 1);
    float acc[8] = {0,0,0,0,0,0,0,0};
#pragma unroll
    for (int kc = 0; kc < 4; kc++) {
        halfx8 p = *(const halfx8*)&part[(((size_t)(kc * 4 + b)) << 20) + le];
#pragma unroll
        for (int e = 0; e < 8; e++) acc[e] += (float)p[e];
    }
    float4 o0 = {acc[0], acc[1], acc[2], acc[3]};
    float4 o1 = {acc[4], acc[5], acc[6], acc[7]};
    ((float4*)(out + E))[0] = o0;
    ((float4*)(out + E))[1] = o1;
}

// ---------------- launch ----------------
extern "C" void kernel_launch(void* const* d_in, const int* in_sizes, int n_in,
                              void* d_out, int out_size, void* d_ws, size_t ws_size,
                              hipStream_t stream) {
    const float* x  = (const float*)d_in[0];
    const float* Wq = (const float*)d_in[1];
    const float* bq = (const float*)d_in[2];
    const float* Wk = (const float*)d_in[3];
    const float* bk = (const float*)d_in[4];
    const float* Wv = (const float*)d_in[5];
    const float* bv = (const float*)d_in[6];
    float* out = (float*)d_out;
    char* ws = (char*)d_ws;

    // ws layout. partial (fp16, written by PV) overlays xh/wcat/bcat (dead after QKV).
    ushort* partial = (ushort*)(ws);                // 33,554,432 (16 slabs fp16 [2048][512])
    ushort* xh      = (ushort*)(ws);                //  8,388,608 (alias, early phase)
    ushort* wcat    = (ushort*)(ws + 8388608);      //  1,572,864 (alias, early phase)
    float*  bcat    = (float*)(ws + 9961472);       //      6,144 (alias, early phase)
    float*  rowsum  = (float*)(ws + 33554432);      //     32,768
    ushort* Pb      = (ushort*)(ws + 33587200);     // 33,554,432 fp16 exp(s)
    ushort* vt      = (ushort*)(ws + 67141632);     //  8,388,608 fp16 v transposed
    ushort* qkh     = (ushort*)(ws + 75530240);     // 33,554,432 fp16 q|k, ld 1024
    // total 109,084,672

    prep_k<<<4874, 256, 0, stream>>>(x, Wq, Wk, Wv, bq, bk, bv, xh, wcat, bcat, rowsum);

    // QKV: q/k -> qkh [8192,1024]; v -> vt [4*512,2048] transposed. K=512.
    gemm_k<0><<<dim3(12, 32, 1), 512, 0, stream>>>(
        xh, wcat, qkh, bcat, nullptr, vt, 512, 512, 1024, 16, 1.0f, 0, 0, 0);

    // scores: P = exp(scale * q@k^T) fp16 [b][2048][2048], rowsum fp32
    const float scale = 0.04419417382415922f;  // 1/sqrt(512)
    gemm_k<1><<<dim3(16, 8, 4), 512, 0, stream>>>(
        qkh, qkh + 512, Pb, nullptr, rowsum, nullptr, 1024, 1024, 2048, 16, scale,
        (long)SEQ * 1024, (long)SEQ * 1024, (long)SEQ * SEQ);

    // PV split-K=4: partial[kc*4+b][2048][512] = (P[:,kc*512:+512] @ vt^T) / rowsum
    gemm_k<2><<<dim3(4, 8, 16), 512, 0, stream>>>(
        Pb, vt, partial, nullptr, rowsum, nullptr, 2048, 2048, 512, 16, 1.0f,
        (long)SEQ * SEQ, (long)DIM * SEQ, (long)SEQ * DIM);

    reduce_k<<<2048, 256, 0, stream>>>(partial, out);
}